// Round 3
// baseline (412.969 us; speedup 1.0000x reference)
//
#include <hip/hip_runtime.h>
#include <math.h>

typedef __bf16 bf16;
typedef __bf16 bf16x4 __attribute__((ext_vector_type(4)));
typedef __bf16 bf16x8 __attribute__((ext_vector_type(8)));
typedef float  f32x4  __attribute__((ext_vector_type(4)));

#define HIDDEN 2048
#define NH     16
#define HD     128
#define BATCH  2
#define SEQ    2048
#define MROWS  (BATCH*SEQ)   // 4096
#define NQKV   (3*HIDDEN)    // 6144

// async global->LDS, 16B per lane. LDS dest must be wave-uniform base + lane*16.
__device__ __forceinline__ void async16(const bf16* g, bf16* l) {
  __builtin_amdgcn_global_load_lds(
      (const __attribute__((address_space(1))) void*)g,
      (__attribute__((address_space(3))) void*)l, 16, 0, 0);
}

// ---------------- cast fp32 -> bf16, vectorized ----------------
__global__ __launch_bounds__(256) void cast_f32_bf16_kernel(
    const float* __restrict__ src, bf16* __restrict__ dst, int n4) {
  int i = blockIdx.x * 256 + threadIdx.x;
  if (i >= n4) return;
  float4 f = ((const float4*)src)[i];
  bf16x4 o;
  o[0] = (bf16)f.x; o[1] = (bf16)f.y; o[2] = (bf16)f.z; o[3] = (bf16)f.w;
  ((bf16x4*)dst)[i] = o;
}

// ---------------- transpose+cast 4x 2048x2048 fp32 W -> bf16 W^T (one launch) ----------------
__global__ __launch_bounds__(256) void transpose_cast4_kernel(
    const float* __restrict__ s0, const float* __restrict__ s1,
    const float* __restrict__ s2, const float* __restrict__ s3,
    bf16* __restrict__ d0, bf16* __restrict__ d1,
    bf16* __restrict__ d2, bf16* __restrict__ d3) {
  const float* src; bf16* dst;
  switch (blockIdx.z) {
    case 0: src = s0; dst = d0; break;
    case 1: src = s1; dst = d1; break;
    case 2: src = s2; dst = d2; break;
    default: src = s3; dst = d3; break;
  }
  __shared__ float t[32][33];
  int x  = blockIdx.x * 32 + threadIdx.x;
  int y0 = blockIdx.y * 32;
#pragma unroll
  for (int i = 0; i < 32; i += 8)
    t[threadIdx.y + i][threadIdx.x] = src[(size_t)(y0 + threadIdx.y + i) * HIDDEN + x];
  __syncthreads();
  int xo  = blockIdx.y * 32 + threadIdx.x;
  int yo0 = blockIdx.x * 32;
#pragma unroll
  for (int i = 0; i < 32; i += 8)
    dst[(size_t)(yo0 + threadIdx.y + i) * HIDDEN + xo] = (bf16)t[threadIdx.x][threadIdx.y + i];
}

// ---------------- concat 3 bias vectors ----------------
__global__ __launch_bounds__(256) void concat3_kernel(
    const float* __restrict__ a, const float* __restrict__ b,
    const float* __restrict__ c, float* __restrict__ dst) {
  int i = blockIdx.x * 256 + threadIdx.x;   // 0..6143
  float v = (i < 2048) ? a[i] : (i < 4096 ? b[i - 2048] : c[i - 4096]);
  dst[i] = v;
}

// ---------------- per-head V transpose: QKV V-part (s,d) -> Vt (bh, d, s) ----------------
__global__ __launch_bounds__(256) void transpose_v_kernel(
    const bf16* __restrict__ QKV, bf16* __restrict__ Vt) {
  __shared__ bf16 t[32][33];
  int bh = blockIdx.z, b = bh >> 4, h = bh & 15;
  const bf16* src = QKV + (size_t)b * SEQ * NQKV + 2 * HIDDEN + h * HD;  // [s][d], stride NQKV
  bf16* dst = Vt + (size_t)bh * HD * SEQ;                                 // [d][s], stride SEQ
  int s0 = blockIdx.x * 32, d0 = blockIdx.y * 32;
#pragma unroll
  for (int i = 0; i < 32; i += 8)
    t[threadIdx.y + i][threadIdx.x] = src[(size_t)(s0 + threadIdx.y + i) * NQKV + d0 + threadIdx.x];
  __syncthreads();
#pragma unroll
  for (int i = 0; i < 32; i += 8)
    dst[(size_t)(d0 + threadIdx.y + i) * SEQ + s0 + threadIdx.x] = t[threadIdx.x][threadIdx.y + i];
}

// ---------------- GEMM: C[M,N] = A[M,K] @ Bt[N,K]^T + bias, bf16 in, fp32 acc ----------------
// PROVEN round-0 structure (888 TF measured, MfmaUtil 39%): 128x128 tile, BK=64 (32 KB LDS),
// 4 waves of 4x4 16x16x32 MFMA, 32 MFMA per barrier-pair. Two phase-scheduled 256-tile
// attempts (r1: 64x64/wave; r2: m201 geometry, vmcnt(2)) both landed at MfmaUtil ~33% --
// prefetch distance 1 phase < memory latency. Reverted; this is at the ~900 TF ceiling
// for the 2-barrier structure.
// Rotation swizzle for 128B rows: physical chunk pc = (c + (row&7))&7; staging thread at
// physical (crow, ccc) fetches data chunk (ccc - crow)&7 so async16 dest stays tid*16.
// Measured conflict-free (SQ_LDS_BANK_CONFLICT = 0).
template <typename OutT>
__global__ __launch_bounds__(256) void gemm_bt_bias(
    const bf16* __restrict__ A, const bf16* __restrict__ Bt,
    const float* __restrict__ bias, OutT* __restrict__ C, int N, int K) {
  __shared__ bf16 Ash[128 * 64];
  __shared__ bf16 Bsh[128 * 64];
  const int tid = threadIdx.x;
  const int wave = tid >> 6, lane = tid & 63, quad = lane >> 4, l16 = lane & 15;
  const int wm = (wave & 1) * 64, wn = (wave >> 1) * 64;
  const int m0 = blockIdx.x * 128, n0 = blockIdx.y * 128;

  const f32x4 zero4 = {0.f, 0.f, 0.f, 0.f};
  f32x4 acc[4][4];
#pragma unroll
  for (int i = 0; i < 4; i++)
#pragma unroll
    for (int j = 0; j < 4; j++) acc[i][j] = zero4;

  const int crow = tid >> 3, ccc = tid & 7;       // 32 rows/pass, 8 chunks/row
  const int cd = (ccc - crow) & 7;                // data chunk staged at physical ccc
  const int l7 = l16 & 7;

  const bf16* pa[4];
  const bf16* pb[4];
#pragma unroll
  for (int s = 0; s < 4; s++) {
    pa[s] = &A[(size_t)(m0 + s * 32 + crow) * K + cd * 8];
    pb[s] = &Bt[(size_t)(n0 + s * 32 + crow) * K + cd * 8];
  }

  for (int kt = 0; kt < K; kt += 64) {
    __syncthreads();
#pragma unroll
    for (int s = 0; s < 4; s++) {
      async16(pa[s], &Ash[s * 2048 + tid * 8]);
      async16(pb[s], &Bsh[s * 2048 + tid * 8]);
      pa[s] += 64; pb[s] += 64;
    }
    __syncthreads();

#pragma unroll
    for (int kk = 0; kk < 2; kk++) {
      const int pc = (kk * 4 + quad + l7) & 7;
      bf16x8 af[4], bfr[4];
#pragma unroll
      for (int i = 0; i < 4; i++) af[i]  = *(const bf16x8*)&Ash[(wm + i * 16 + l16) * 64 + pc * 8];
#pragma unroll
      for (int j = 0; j < 4; j++) bfr[j] = *(const bf16x8*)&Bsh[(wn + j * 16 + l16) * 64 + pc * 8];
#pragma unroll
      for (int i = 0; i < 4; i++)
#pragma unroll
        for (int j = 0; j < 4; j++)
          acc[i][j] = __builtin_amdgcn_mfma_f32_16x16x32_bf16(af[i], bfr[j], acc[i][j], 0, 0, 0);
    }
  }

#pragma unroll
  for (int i = 0; i < 4; i++)
#pragma unroll
    for (int j = 0; j < 4; j++) {
      int n = n0 + wn + j * 16 + l16;
      float bv = bias[n];
#pragma unroll
      for (int r = 0; r < 4; r++) {
        int m = m0 + wm + i * 16 + quad * 4 + r;
        C[(size_t)m * N + n] = (OutT)(acc[i][j][r] + bv);
      }
    }
}

// ---------------- flash attention, double-buffered K/V (T3-minimum 2-phase) ----------------
// block: 128 q-rows (4 waves x 32 rows), K-tiles of 64 keys, D=128.
// Pipeline: stage(t+1) issued at tile start -> counted vmcnt(8) (waits only tile t's 8
// loads, issued one FULL tile of compute earlier) -> barrier -> compute (no internal
// barriers: P is wave-private) -> trailing barrier (frees buf for t+2's stage).
// Exposes zero serial staging latency vs the old sync-stage-sync (32x per block).
// LDS: K 2x16KB + V 2x16KB + P 16KB = 80 KB exactly -> keeps 2 blocks/CU.
// Psh shrunk from [128][72] pad to [128][64] via XOR swizzle: phys_byte = q*128 + col*2
// XOR ((q&7)<<4). Read banks 4*((quad+(q&7))&7) -> 2-way max (free); writes 4-way
// (8 stores/tile, negligible). Both accesses keep 8B/16B alignment (XOR bits 4-6 only).
// XCD swizzle: pack each bh's 16 q-blocks on one XCD (K/V 1MB x 4bh = 4MB fits L2),
// turning cross-block K/V re-reads into L2 hits (shorter latency for the vmcnt).
// S^T formulation unchanged: mfma(kf, qf) puts q on lane axis, key on reg axis.
#define KTS   64

__global__ __launch_bounds__(256, 2) void flash_attn_kernel(
    const bf16* __restrict__ QKV, const bf16* __restrict__ Vt, bf16* __restrict__ O) {
  // XCD-aware swizzle of the 512-block grid (16 q-blocks x 32 bh)
  const int fid = blockIdx.x + 16 * blockIdx.y;
  const int nid = (fid & 7) * 64 + (fid >> 3);   // XCD x owns bh 4x..4x+3, all q-blocks
  const int bh = nid >> 4, b = bh >> 4, h = bh & 15;
  const int q0 = (nid & 15) * 128;
  const int tid = threadIdx.x, wave = tid >> 6, lane = tid & 63, quad = lane >> 4, l16 = lane & 15;

  const bf16* Qb  = QKV + (size_t)b * SEQ * NQKV + h * HD;            // Q[s][d], stride NQKV
  const bf16* Kb  = QKV + (size_t)b * SEQ * NQKV + HIDDEN + h * HD;   // K[s][d], stride NQKV
  const bf16* Vtb = Vt + (size_t)bh * HD * SEQ;                       // Vt[d][s], stride SEQ

  __shared__ bf16 Ksh[2][KTS * HD];  // [key][d], swizzled chunks, 2 x 16 KB
  __shared__ bf16 Vsh[2][HD * KTS];  // [d][key], swizzled chunks, 2 x 16 KB
  __shared__ bf16 Psh[128 * 64];     // [q][key], XOR-swizzled, 16 KB

  const int qrow = q0 + wave * 32;
  const float sc = 0.08838834764831845f * 1.44269504088896340f;  // 1/sqrt(128) * log2(e)

  // Q fragments (B-operand; lane layout as before), pre-scaled by sc
  bf16x8 qf[2][4];
#pragma unroll
  for (int mt = 0; mt < 2; mt++)
#pragma unroll
    for (int kk = 0; kk < 4; kk++) {
      bf16x8 t = *(const bf16x8*)&Qb[(size_t)(qrow + mt * 16 + l16) * NQKV + kk * 32 + quad * 8];
#pragma unroll
      for (int j = 0; j < 8; j++) t[j] = (bf16)((float)t[j] * sc);
      qf[mt][kk] = t;
    }

  const f32x4 zero4 = {0.f, 0.f, 0.f, 0.f};
  f32x4 oacc[2][8];
#pragma unroll
  for (int mt = 0; mt < 2; mt++)
#pragma unroll
    for (int nt = 0; nt < 8; nt++) oacc[mt][nt] = zero4;

  float lrun[2] = {0.f, 0.f};   // per-lane: l for q = qrow + mt*16 + l16

  const int krp = tid >> 4, kpp = tid & 15;  // K staging: physical row/chunk
  const int vrp = tid >> 3, vpp = tid & 7;   // V staging
  const int l7 = l16 & 7;

  // hoisted staging pointers (global side carries the rotation pre-swizzle)
  const bf16* pk[4];
  const bf16* pv[4];
#pragma unroll
  for (int s = 0; s < 4; s++) {
    int r  = s * 16 + krp;
    pk[s] = &Kb[(size_t)r * NQKV + (kpp ^ (r & 7)) * 8];
    int rv = s * 32 + vrp;
    pv[s] = &Vtb[(size_t)rv * SEQ + (vpp ^ (rv & 7)) * 8];
  }

  // ---- prologue: stage tile 0 into buf 0 ----
#pragma unroll
  for (int s = 0; s < 4; s++) {
    async16(pk[s], &Ksh[0][s * 2048 + tid * 8]);
    async16(pv[s], &Vsh[0][s * 2048 + tid * 8]);
    pk[s] += (size_t)KTS * NQKV;
    pv[s] += KTS;
  }

  const int NT = SEQ / KTS;   // 32
  for (int t = 0; t < NT; ++t) {
    const int cur = t & 1;
    // stage tile t+1 into the other buffer (its last readers finished at t-1's
    // trailing barrier); loads stay in flight across this tile's compute.
    if (t + 1 < NT) {
#pragma unroll
      for (int s = 0; s < 4; s++) {
        async16(pk[s], &Ksh[cur ^ 1][s * 2048 + tid * 8]);
        async16(pv[s], &Vsh[cur ^ 1][s * 2048 + tid * 8]);
        pk[s] += (size_t)KTS * NQKV;
        pv[s] += KTS;
      }
      asm volatile("s_waitcnt vmcnt(8)" ::: "memory");  // oldest 8 = tile t landed
    } else {
      asm volatile("s_waitcnt vmcnt(0)" ::: "memory");
    }
    __builtin_amdgcn_s_barrier();  // every wave's tile-t loads landed -> LDS consistent

    // S^T = K @ Qs^T : C col = l16 = q, row = quad*4+r = key
    f32x4 st[2][4];
#pragma unroll
    for (int mt = 0; mt < 2; mt++)
#pragma unroll
      for (int nt = 0; nt < 4; nt++) st[mt][nt] = zero4;
#pragma unroll
    for (int kk = 0; kk < 4; kk++) {
      const int p = (4 * kk + quad) ^ l7;   // physical chunk (un-swizzle)
      bf16x8 kf[4];
#pragma unroll
      for (int nt = 0; nt < 4; nt++)
        kf[nt] = *(const bf16x8*)&Ksh[cur][(nt * 16 + l16) * HD + p * 8];
      __builtin_amdgcn_s_setprio(1);
#pragma unroll
      for (int mt = 0; mt < 2; mt++)
#pragma unroll
        for (int nt = 0; nt < 4; nt++)
          st[mt][nt] = __builtin_amdgcn_mfma_f32_16x16x32_bf16(kf[nt], qf[mt][kk], st[mt][nt], 0, 0, 0);
      __builtin_amdgcn_s_setprio(0);
    }

    // p = exp2(s); packed b64 P-write (4 consecutive keys of one q, XOR-swizzled);
    // lane-local sums. P rows are wave-private: no barrier needed before PV.
    float rs[2] = {0.f, 0.f};
#pragma unroll
    for (int mt = 0; mt < 2; mt++)
#pragma unroll
      for (int nt = 0; nt < 4; nt++) {
        bf16x4 pk4;
#pragma unroll
        for (int r = 0; r < 4; r++) {
          float p = exp2f(st[mt][nt][r]);
          rs[mt] += p;
          pk4[r] = (bf16)p;
        }
        int pbyte = ((wave * 32 + mt * 16 + l16) * 64 + nt * 16 + quad * 4) * 2;
        pbyte ^= (l16 & 7) << 4;
        *(bf16x4*)((char*)Psh + pbyte) = pk4;
      }
#pragma unroll
    for (int mt = 0; mt < 2; mt++) {
      float t2 = rs[mt];
      t2 += __shfl_xor(t2, 16);
      t2 += __shfl_xor(t2, 32);
      lrun[mt] += t2;
    }

    // O += P @ V  (P rows are this wave's own rows)
#pragma unroll
    for (int kk2 = 0; kk2 < 2; kk2++) {
      bf16x8 pf[2], vf[8];
#pragma unroll
      for (int mt = 0; mt < 2; mt++) {
        int pbyte = ((wave * 32 + mt * 16 + l16) * 64 + kk2 * 32 + quad * 8) * 2;
        pbyte ^= (l16 & 7) << 4;
        pf[mt] = *(const bf16x8*)((char*)Psh + pbyte);
      }
#pragma unroll
      for (int nt = 0; nt < 8; nt++) {
        int p = (4 * kk2 + quad) ^ l7;  // physical chunk (un-swizzle)
        vf[nt] = *(const bf16x8*)&Vsh[cur][(nt * 16 + l16) * KTS + p * 8];
      }
      __builtin_amdgcn_s_setprio(1);
#pragma unroll
      for (int mt = 0; mt < 2; mt++)
#pragma unroll
        for (int nt = 0; nt < 8; nt++)
          oacc[mt][nt] = __builtin_amdgcn_mfma_f32_16x16x32_bf16(pf[mt], vf[nt], oacc[mt][nt], 0, 0, 0);
      __builtin_amdgcn_s_setprio(0);
    }

    __builtin_amdgcn_s_barrier();  // all waves done reading tile t -> buf free for t+2
  }

  // epilogue: O[q][h*128+d] = oacc / l.  l for q=mt*16+x lives at lanes with l16=x.
#pragma unroll
  for (int mt = 0; mt < 2; mt++) {
    float inv[4];
#pragma unroll
    for (int r = 0; r < 4; r++)
      inv[r] = 1.0f / __shfl(lrun[mt], (lane & 48) | (quad * 4 + r));
#pragma unroll
    for (int nt = 0; nt < 8; nt++)
#pragma unroll
      for (int r = 0; r < 4; r++) {
        int q = qrow + mt * 16 + quad * 4 + r;
        int d = nt * 16 + l16;
        O[(size_t)(b * SEQ + q) * HIDDEN + h * HD + d] = (bf16)(oacc[mt][nt][r] * inv[r]);
      }
  }
}

extern "C" void kernel_launch(void* const* d_in, const int* in_sizes, int n_in,
                              void* d_out, int out_size, void* d_ws, size_t ws_size,
                              hipStream_t stream) {
  const float* hs = (const float*)d_in[0];
  const float* Wq = (const float*)d_in[1];
  const float* bq = (const float*)d_in[2];
  const float* Wk = (const float*)d_in[3];
  const float* bk = (const float*)d_in[4];
  const float* Wv = (const float*)d_in[5];
  const float* bv = (const float*)d_in[6];
  const float* Wo = (const float*)d_in[7];
  const float* bo = (const float*)d_in[8];
  float* out = (float*)d_out;

  char* ws = (char*)d_ws;
  bf16*  Abf   = (bf16*)(ws);                    // 4096*2048*2   = 16,777,216
  bf16*  WtQKV = (bf16*)(ws + 16777216);         // 6144*2048*2   = 25,165,824
  bf16*  WtO   = (bf16*)(ws + 41943040);         // 2048*2048*2   =  8,388,608
  float* biasQ = (float*)(ws + 50331648);        // 6144*4        =     24,576
  bf16*  QKV   = (bf16*)(ws + 50356224);         // 4096*6144*2   = 50,331,648
  bf16*  VT    = (bf16*)(ws + 100687872);        // 32*128*2048*2 = 16,777,216
  bf16*  Obf   = (bf16*)(ws + 117465088);        // 4096*2048*2   = 16,777,216
  // total 134,242,304 bytes of d_ws

  dim3 tb(32, 8);
  cast_f32_bf16_kernel<<<8192, 256, 0, stream>>>(hs, Abf, 2097152);
  transpose_cast4_kernel<<<dim3(64, 64, 4), tb, 0, stream>>>(
      Wq, Wk, Wv, Wo,
      WtQKV, WtQKV + 2048 * 2048, WtQKV + 2 * 2048 * 2048, WtO);
  concat3_kernel<<<24, 256, 0, stream>>>(bq, bk, bv, biasQ);

  gemm_bt_bias<bf16><<<dim3(32, 48), 256, 0, stream>>>(Abf, WtQKV, biasQ, QKV, NQKV, HIDDEN);
  transpose_v_kernel<<<dim3(64, 4, 32), tb, 0, stream>>>(QKV, VT);
  flash_attn_kernel<<<dim3(16, 32), 256, 0, stream>>>(QKV, VT, Obf);
  gemm_bt_bias<float><<<dim3(32, 16), 256, 0, stream>>>(Obf, WtO, bo, out, HIDDEN, HIDDEN);
}

// Round 4
// 408.371 us; speedup vs baseline: 1.0113x; 1.0113x over previous
//
#include <hip/hip_runtime.h>
#include <math.h>

typedef __bf16 bf16;
typedef __bf16 bf16x4 __attribute__((ext_vector_type(4)));
typedef __bf16 bf16x8 __attribute__((ext_vector_type(8)));
typedef float  f32x4  __attribute__((ext_vector_type(4)));

#define HIDDEN 2048
#define NH     16
#define HD     128
#define BATCH  2
#define SEQ    2048
#define MROWS  (BATCH*SEQ)   // 4096
#define NQKV   (3*HIDDEN)    // 6144

// async global->LDS, 16B per lane. LDS dest must be wave-uniform base + lane*16.
__device__ __forceinline__ void async16(const bf16* g, bf16* l) {
  __builtin_amdgcn_global_load_lds(
      (const __attribute__((address_space(1))) void*)g,
      (__attribute__((address_space(3))) void*)l, 16, 0, 0);
}

// ---------------- cast fp32 -> bf16, vectorized ----------------
__global__ __launch_bounds__(256) void cast_f32_bf16_kernel(
    const float* __restrict__ src, bf16* __restrict__ dst, int n4) {
  int i = blockIdx.x * 256 + threadIdx.x;
  if (i >= n4) return;
  float4 f = ((const float4*)src)[i];
  bf16x4 o;
  o[0] = (bf16)f.x; o[1] = (bf16)f.y; o[2] = (bf16)f.z; o[3] = (bf16)f.w;
  ((bf16x4*)dst)[i] = o;
}

// ---------------- transpose+cast 4x 2048x2048 fp32 W -> bf16 W^T (one launch) ----------------
__global__ __launch_bounds__(256) void transpose_cast4_kernel(
    const float* __restrict__ s0, const float* __restrict__ s1,
    const float* __restrict__ s2, const float* __restrict__ s3,
    bf16* __restrict__ d0, bf16* __restrict__ d1,
    bf16* __restrict__ d2, bf16* __restrict__ d3) {
  const float* src; bf16* dst;
  switch (blockIdx.z) {
    case 0: src = s0; dst = d0; break;
    case 1: src = s1; dst = d1; break;
    case 2: src = s2; dst = d2; break;
    default: src = s3; dst = d3; break;
  }
  __shared__ float t[32][33];
  int x  = blockIdx.x * 32 + threadIdx.x;
  int y0 = blockIdx.y * 32;
#pragma unroll
  for (int i = 0; i < 32; i += 8)
    t[threadIdx.y + i][threadIdx.x] = src[(size_t)(y0 + threadIdx.y + i) * HIDDEN + x];
  __syncthreads();
  int xo  = blockIdx.y * 32 + threadIdx.x;
  int yo0 = blockIdx.x * 32;
#pragma unroll
  for (int i = 0; i < 32; i += 8)
    dst[(size_t)(yo0 + threadIdx.y + i) * HIDDEN + xo] = (bf16)t[threadIdx.x][threadIdx.y + i];
}

// ---------------- concat 3 bias vectors ----------------
__global__ __launch_bounds__(256) void concat3_kernel(
    const float* __restrict__ a, const float* __restrict__ b,
    const float* __restrict__ c, float* __restrict__ dst) {
  int i = blockIdx.x * 256 + threadIdx.x;   // 0..6143
  float v = (i < 2048) ? a[i] : (i < 4096 ? b[i - 2048] : c[i - 4096]);
  dst[i] = v;
}

// ---------------- per-head V transpose: QKV V-part (s,d) -> Vt (bh, d, s) ----------------
__global__ __launch_bounds__(256) void transpose_v_kernel(
    const bf16* __restrict__ QKV, bf16* __restrict__ Vt) {
  __shared__ bf16 t[32][33];
  int bh = blockIdx.z, b = bh >> 4, h = bh & 15;
  const bf16* src = QKV + (size_t)b * SEQ * NQKV + 2 * HIDDEN + h * HD;  // [s][d], stride NQKV
  bf16* dst = Vt + (size_t)bh * HD * SEQ;                                 // [d][s], stride SEQ
  int s0 = blockIdx.x * 32, d0 = blockIdx.y * 32;
#pragma unroll
  for (int i = 0; i < 32; i += 8)
    t[threadIdx.y + i][threadIdx.x] = src[(size_t)(s0 + threadIdx.y + i) * NQKV + d0 + threadIdx.x];
  __syncthreads();
#pragma unroll
  for (int i = 0; i < 32; i += 8)
    dst[(size_t)(d0 + threadIdx.y + i) * SEQ + s0 + threadIdx.x] = t[threadIdx.x][threadIdx.y + i];
}

// ---------------- GEMM 128x128 (proven, 888 TF): O-proj ----------------
// 128x128 tile, BK=64 (32 KB LDS), 4 waves of 4x4 16x16x32 MFMA, 32 MFMA per barrier-pair.
// Rotation swizzle: physical chunk pc = (c + (row&7))&7; measured conflict-free.
template <typename OutT>
__global__ __launch_bounds__(256) void gemm_bt_bias(
    const bf16* __restrict__ A, const bf16* __restrict__ Bt,
    const float* __restrict__ bias, OutT* __restrict__ C, int N, int K) {
  __shared__ bf16 Ash[128 * 64];
  __shared__ bf16 Bsh[128 * 64];
  const int tid = threadIdx.x;
  const int wave = tid >> 6, lane = tid & 63, quad = lane >> 4, l16 = lane & 15;
  const int wm = (wave & 1) * 64, wn = (wave >> 1) * 64;
  const int m0 = blockIdx.x * 128, n0 = blockIdx.y * 128;

  const f32x4 zero4 = {0.f, 0.f, 0.f, 0.f};
  f32x4 acc[4][4];
#pragma unroll
  for (int i = 0; i < 4; i++)
#pragma unroll
    for (int j = 0; j < 4; j++) acc[i][j] = zero4;

  const int crow = tid >> 3, ccc = tid & 7;       // 32 rows/pass, 8 chunks/row
  const int cd = (ccc - crow) & 7;                // data chunk staged at physical ccc
  const int l7 = l16 & 7;

  const bf16* pa[4];
  const bf16* pb[4];
#pragma unroll
  for (int s = 0; s < 4; s++) {
    pa[s] = &A[(size_t)(m0 + s * 32 + crow) * K + cd * 8];
    pb[s] = &Bt[(size_t)(n0 + s * 32 + crow) * K + cd * 8];
  }

  for (int kt = 0; kt < K; kt += 64) {
    __syncthreads();
#pragma unroll
    for (int s = 0; s < 4; s++) {
      async16(pa[s], &Ash[s * 2048 + tid * 8]);
      async16(pb[s], &Bsh[s * 2048 + tid * 8]);
      pa[s] += 64; pb[s] += 64;
    }
    __syncthreads();

#pragma unroll
    for (int kk = 0; kk < 2; kk++) {
      const int pc = (kk * 4 + quad + l7) & 7;
      bf16x8 af[4], bfr[4];
#pragma unroll
      for (int i = 0; i < 4; i++) af[i]  = *(const bf16x8*)&Ash[(wm + i * 16 + l16) * 64 + pc * 8];
#pragma unroll
      for (int j = 0; j < 4; j++) bfr[j] = *(const bf16x8*)&Bsh[(wn + j * 16 + l16) * 64 + pc * 8];
#pragma unroll
      for (int i = 0; i < 4; i++)
#pragma unroll
        for (int j = 0; j < 4; j++)
          acc[i][j] = __builtin_amdgcn_mfma_f32_16x16x32_bf16(af[i], bfr[j], acc[i][j], 0, 0, 0);
    }
  }

#pragma unroll
  for (int i = 0; i < 4; i++)
#pragma unroll
    for (int j = 0; j < 4; j++) {
      int n = n0 + wn + j * 16 + l16;
      float bv = bias[n];
#pragma unroll
      for (int r = 0; r < 4; r++) {
        int m = m0 + wm + i * 16 + quad * 4 + r;
        C[(size_t)m * N + n] = (OutT)(acc[i][j][r] + bv);
      }
    }
}

// ---------------- GEMM 256x256, depth-2 prefetch phase schedule: QKV projection ----------------
// BM=BN=256, BK=64, 512 threads = 8 waves (2 x 4), per-wave output 128x64 (acc 8x4 f32x4).
// LDS = 2 dbuf x (A 2x[128x64] + B 2x[128x64]) = 128 KiB -> 1 block/CU; ALL latency hiding
// must come from the in-block pipeline (r2 lesson: depth-1 prefetch => MfmaUtil 33%).
// Depth-2 schedule: while computing tile t from buf (t&1), stage tile t+2 into the SAME
// buffer at ph3 (B halves) / ph4 (A halves); one counted vmcnt(8) at ph4-end confirms
// tile t+1 (staged one full tile = ~4 phases = ~1000 cyc earlier) while t+2's 8 loads
// stay in flight. Steady state: 16 loads in flight, never drained mid-loop.
// Race ledger (stage into the buffer being read):
//   - ph3 stageB overwrites buf B: last B ds_reads are ph2's, completed at each wave's
//     ph2 lgkmcnt(0) < ph2 trailing barrier < any wave's ph3 stage issue.  SAFE.
//   - ph4 stageA overwrites buf A: last A ds_reads are ph3's, completed at ph3 lgkmcnt(0)
//     < ph3 trailing barrier < ph4 stage issue.  SAFE.
//   - reads of tile t+1 (ph1 of next iteration) gated by this vmcnt(8) + barrier:
//     each wave waits its own loads, barrier makes it collective.  SAFE.
// vmcnt arithmetic: at ph4-end, the 8 newest outstanding loads are t+2's (ph3:4 + ph4:4);
// vmcnt(8) => everything older (= t+1's 8, issued last iteration) has landed.
// Tail: when t+2 >= NT nothing staged -> vmcnt(0).
// Rotation swizzle identical to the 128x128 kernel (measured conflict-free).
template <typename OutT>
__global__ __launch_bounds__(512, 2) void gemm_bt_bias_256(
    const bf16* __restrict__ A, const bf16* __restrict__ Bt,
    const float* __restrict__ bias, OutT* __restrict__ C, int N, int K) {
  __shared__ bf16 Ash[2][2][128 * 64];   // [dbuf][half][row*64+col], 64 KiB
  __shared__ bf16 Bsh[2][2][128 * 64];   // 64 KiB

  const int tid = threadIdx.x;
  const int wave = tid >> 6, lane = tid & 63, quad = lane >> 4, l16 = lane & 15, l7 = l16 & 7;
  const int hA = wave >> 2;                        // A half this wave consumes (rows hA*128..)
  const int wnq = wave & 3;                        // N quarter
  const int hB = wnq >> 1, rB0 = (wnq & 1) * 64;   // B half + row offset within half
  const int m0 = blockIdx.x * 256, n0 = blockIdx.y * 256;

  const f32x4 zero4 = {0.f, 0.f, 0.f, 0.f};
  f32x4 acc[8][4];
#pragma unroll
  for (int i = 0; i < 8; i++)
#pragma unroll
    for (int j = 0; j < 4; j++) acc[i][j] = zero4;

  const int crow = tid >> 3, ccc = tid & 7;    // 64 rows/pass, 8 chunks/row
  const int cd = (ccc - crow) & 7;             // data chunk staged at physical ccc

  const bf16* gA[2][2];
  const bf16* gB[2][2];
#pragma unroll
  for (int h = 0; h < 2; h++)
#pragma unroll
    for (int s = 0; s < 2; s++) {
      gA[h][s] = &A[(size_t)(m0 + h * 128 + s * 64 + crow) * K + cd * 8];
      gB[h][s] = &Bt[(size_t)(n0 + h * 128 + s * 64 + crow) * K + cd * 8];
    }

  auto stageA = [&](int buf, int h) {
    async16(gA[h][0], &Ash[buf][h][0 * 4096 + tid * 8]); gA[h][0] += 64;
    async16(gA[h][1], &Ash[buf][h][1 * 4096 + tid * 8]); gA[h][1] += 64;
  };
  auto stageB = [&](int buf, int h) {
    async16(gB[h][0], &Bsh[buf][h][0 * 4096 + tid * 8]); gB[h][0] += 64;
    async16(gB[h][1], &Bsh[buf][h][1 * 4096 + tid * 8]); gB[h][1] += 64;
  };

  const int NT = K >> 6;   // 64-wide K-tiles (>= 2 assumed)

  // ---- prologue: tile0 -> buf0 (8 loads), tile1 -> buf1 (8); wait tile0, keep tile1 in flight
  stageB(0, 0); stageB(0, 1); stageA(0, 0); stageA(0, 1);
  stageB(1, 0); stageB(1, 1); stageA(1, 0); stageA(1, 1);
  asm volatile("s_waitcnt vmcnt(8)" ::: "memory");
  __builtin_amdgcn_s_barrier();

  for (int t = 0; t < NT; ++t) {
    const int cur = t & 1;
    const bool st = (t + 2 < NT);
    const bf16* Ab = Ash[cur][hA];
    const bf16* Bb = Bsh[cur][hB];

    bf16x8 af[4][2], bfr[4][2];

    // ---- ph1: read A rows 0-63 (af, 8) + B rows 0-31 (bfr01, 4); Q1 = mi0-3 x ni0-1 ----
#pragma unroll
    for (int mi = 0; mi < 4; mi++)
#pragma unroll
      for (int ks = 0; ks < 2; ks++)
        af[mi][ks] = *(const bf16x8*)&Ab[(mi * 16 + l16) * 64 + (((ks * 4 + quad) + l7) & 7) * 8];
#pragma unroll
    for (int ni = 0; ni < 2; ni++)
#pragma unroll
      for (int ks = 0; ks < 2; ks++)
        bfr[ni][ks] = *(const bf16x8*)&Bb[(rB0 + ni * 16 + l16) * 64 + (((ks * 4 + quad) + l7) & 7) * 8];
    __builtin_amdgcn_s_barrier();
    asm volatile("s_waitcnt lgkmcnt(0)" ::: "memory");
    __builtin_amdgcn_sched_barrier(0);
    __builtin_amdgcn_s_setprio(1);
#pragma unroll
    for (int ks = 0; ks < 2; ks++)
#pragma unroll
      for (int mi = 0; mi < 4; mi++)
#pragma unroll
        for (int ni = 0; ni < 2; ni++)
          acc[mi][ni] = __builtin_amdgcn_mfma_f32_16x16x32_bf16(af[mi][ks], bfr[ni][ks], acc[mi][ni], 0, 0, 0);
    __builtin_amdgcn_s_setprio(0);
    __builtin_amdgcn_s_barrier();

    // ---- ph2: read B rows 32-63 (bfr23, 4); Q2 = mi0-3 x ni2-3 ----
#pragma unroll
    for (int ni = 2; ni < 4; ni++)
#pragma unroll
      for (int ks = 0; ks < 2; ks++)
        bfr[ni][ks] = *(const bf16x8*)&Bb[(rB0 + ni * 16 + l16) * 64 + (((ks * 4 + quad) + l7) & 7) * 8];
    __builtin_amdgcn_s_barrier();
    asm volatile("s_waitcnt lgkmcnt(0)" ::: "memory");
    __builtin_amdgcn_sched_barrier(0);
    __builtin_amdgcn_s_setprio(1);
#pragma unroll
    for (int ks = 0; ks < 2; ks++)
#pragma unroll
      for (int mi = 0; mi < 4; mi++)
#pragma unroll
        for (int ni = 2; ni < 4; ni++)
          acc[mi][ni] = __builtin_amdgcn_mfma_f32_16x16x32_bf16(af[mi][ks], bfr[ni][ks], acc[mi][ni], 0, 0, 0);
    __builtin_amdgcn_s_setprio(0);
    __builtin_amdgcn_s_barrier();

    // ---- ph3: read A rows 64-127 (af reuse, 8); stage B(t+2) into CUR buf (safe: B's
    //           last readers finished before ph2's trailing barrier); Q3 = mi4-7 x ni0-1 ----
#pragma unroll
    for (int mi = 0; mi < 4; mi++)
#pragma unroll
      for (int ks = 0; ks < 2; ks++)
        af[mi][ks] = *(const bf16x8*)&Ab[((mi + 4) * 16 + l16) * 64 + (((ks * 4 + quad) + l7) & 7) * 8];
    if (st) { stageB(cur, 0); stageB(cur, 1); }
    __builtin_amdgcn_s_barrier();
    asm volatile("s_waitcnt lgkmcnt(0)" ::: "memory");
    __builtin_amdgcn_sched_barrier(0);
    __builtin_amdgcn_s_setprio(1);
#pragma unroll
    for (int ks = 0; ks < 2; ks++)
#pragma unroll
      for (int mi = 0; mi < 4; mi++)
#pragma unroll
        for (int ni = 0; ni < 2; ni++)
          acc[4 + mi][ni] = __builtin_amdgcn_mfma_f32_16x16x32_bf16(af[mi][ks], bfr[ni][ks], acc[4 + mi][ni], 0, 0, 0);
    __builtin_amdgcn_s_setprio(0);
    __builtin_amdgcn_s_barrier();

    // ---- ph4: stage A(t+2) into CUR buf (safe: A's last readers finished before ph3's
    //           trailing barrier); Q4 = mi4-7 x ni2-3; counted vmcnt fences tile t+1 ----
    if (st) { stageA(cur, 0); stageA(cur, 1); }
    __builtin_amdgcn_s_setprio(1);
#pragma unroll
    for (int ks = 0; ks < 2; ks++)
#pragma unroll
      for (int mi = 0; mi < 4; mi++)
#pragma unroll
        for (int ni = 2; ni < 4; ni++)
          acc[4 + mi][ni] = __builtin_amdgcn_mfma_f32_16x16x32_bf16(af[mi][ks], bfr[ni][ks], acc[4 + mi][ni], 0, 0, 0);
    __builtin_amdgcn_s_setprio(0);
    if (st) asm volatile("s_waitcnt vmcnt(8)" ::: "memory");   // t+1 landed, t+2 in flight
    else    asm volatile("s_waitcnt vmcnt(0)" ::: "memory");   // tail: drain
    __builtin_amdgcn_s_barrier();
  }

  // C/D layout: col = lane&15, row = quad*4 + reg
#pragma unroll
  for (int mi = 0; mi < 8; mi++)
#pragma unroll
    for (int ni = 0; ni < 4; ni++) {
      int n = n0 + wnq * 64 + ni * 16 + l16;
      float bv = bias[n];
#pragma unroll
      for (int r = 0; r < 4; r++) {
        int m = m0 + hA * 128 + mi * 16 + quad * 4 + r;
        C[(size_t)m * N + n] = (OutT)(acc[mi][ni][r] + bv);
      }
    }
}

// ---------------- flash attention, double-buffered K/V (round-3 version, neutral-verified) ----
#define KTS   64

__global__ __launch_bounds__(256, 2) void flash_attn_kernel(
    const bf16* __restrict__ QKV, const bf16* __restrict__ Vt, bf16* __restrict__ O) {
  // XCD-aware swizzle of the 512-block grid (16 q-blocks x 32 bh)
  const int fid = blockIdx.x + 16 * blockIdx.y;
  const int nid = (fid & 7) * 64 + (fid >> 3);   // XCD x owns bh 4x..4x+3, all q-blocks
  const int bh = nid >> 4, b = bh >> 4, h = bh & 15;
  const int q0 = (nid & 15) * 128;
  const int tid = threadIdx.x, wave = tid >> 6, lane = tid & 63, quad = lane >> 4, l16 = lane & 15;

  const bf16* Qb  = QKV + (size_t)b * SEQ * NQKV + h * HD;            // Q[s][d], stride NQKV
  const bf16* Kb  = QKV + (size_t)b * SEQ * NQKV + HIDDEN + h * HD;   // K[s][d], stride NQKV
  const bf16* Vtb = Vt + (size_t)bh * HD * SEQ;                       // Vt[d][s], stride SEQ

  __shared__ bf16 Ksh[2][KTS * HD];  // [key][d], swizzled chunks, 2 x 16 KB
  __shared__ bf16 Vsh[2][HD * KTS];  // [d][key], swizzled chunks, 2 x 16 KB
  __shared__ bf16 Psh[128 * 64];     // [q][key], XOR-swizzled, 16 KB

  const int qrow = q0 + wave * 32;
  const float sc = 0.08838834764831845f * 1.44269504088896340f;  // 1/sqrt(128) * log2(e)

  // Q fragments (B-operand; lane layout as before), pre-scaled by sc
  bf16x8 qf[2][4];
#pragma unroll
  for (int mt = 0; mt < 2; mt++)
#pragma unroll
    for (int kk = 0; kk < 4; kk++) {
      bf16x8 t = *(const bf16x8*)&Qb[(size_t)(qrow + mt * 16 + l16) * NQKV + kk * 32 + quad * 8];
#pragma unroll
      for (int j = 0; j < 8; j++) t[j] = (bf16)((float)t[j] * sc);
      qf[mt][kk] = t;
    }

  const f32x4 zero4 = {0.f, 0.f, 0.f, 0.f};
  f32x4 oacc[2][8];
#pragma unroll
  for (int mt = 0; mt < 2; mt++)
#pragma unroll
    for (int nt = 0; nt < 8; nt++) oacc[mt][nt] = zero4;

  float lrun[2] = {0.f, 0.f};   // per-lane: l for q = qrow + mt*16 + l16

  const int krp = tid >> 4, kpp = tid & 15;  // K staging: physical row/chunk
  const int vrp = tid >> 3, vpp = tid & 7;   // V staging
  const int l7 = l16 & 7;

  // hoisted staging pointers (global side carries the rotation pre-swizzle)
  const bf16* pk[4];
  const bf16* pv[4];
#pragma unroll
  for (int s = 0; s < 4; s++) {
    int r  = s * 16 + krp;
    pk[s] = &Kb[(size_t)r * NQKV + (kpp ^ (r & 7)) * 8];
    int rv = s * 32 + vrp;
    pv[s] = &Vtb[(size_t)rv * SEQ + (vpp ^ (rv & 7)) * 8];
  }

  // ---- prologue: stage tile 0 into buf 0 ----
#pragma unroll
  for (int s = 0; s < 4; s++) {
    async16(pk[s], &Ksh[0][s * 2048 + tid * 8]);
    async16(pv[s], &Vsh[0][s * 2048 + tid * 8]);
    pk[s] += (size_t)KTS * NQKV;
    pv[s] += KTS;
  }

  const int NT = SEQ / KTS;   // 32
  for (int t = 0; t < NT; ++t) {
    const int cur = t & 1;
    if (t + 1 < NT) {
#pragma unroll
      for (int s = 0; s < 4; s++) {
        async16(pk[s], &Ksh[cur ^ 1][s * 2048 + tid * 8]);
        async16(pv[s], &Vsh[cur ^ 1][s * 2048 + tid * 8]);
        pk[s] += (size_t)KTS * NQKV;
        pv[s] += KTS;
      }
      asm volatile("s_waitcnt vmcnt(8)" ::: "memory");  // oldest 8 = tile t landed
    } else {
      asm volatile("s_waitcnt vmcnt(0)" ::: "memory");
    }
    __builtin_amdgcn_s_barrier();  // every wave's tile-t loads landed -> LDS consistent

    // S^T = K @ Qs^T : C col = l16 = q, row = quad*4+r = key
    f32x4 st[2][4];
#pragma unroll
    for (int mt = 0; mt < 2; mt++)
#pragma unroll
      for (int nt = 0; nt < 4; nt++) st[mt][nt] = zero4;
#pragma unroll
    for (int kk = 0; kk < 4; kk++) {
      const int p = (4 * kk + quad) ^ l7;   // physical chunk (un-swizzle)
      bf16x8 kf[4];
#pragma unroll
      for (int nt = 0; nt < 4; nt++)
        kf[nt] = *(const bf16x8*)&Ksh[cur][(nt * 16 + l16) * HD + p * 8];
      __builtin_amdgcn_s_setprio(1);
#pragma unroll
      for (int mt = 0; mt < 2; mt++)
#pragma unroll
        for (int nt = 0; nt < 4; nt++)
          st[mt][nt] = __builtin_amdgcn_mfma_f32_16x16x32_bf16(kf[nt], qf[mt][kk], st[mt][nt], 0, 0, 0);
      __builtin_amdgcn_s_setprio(0);
    }

    // p = exp2(s); packed b64 P-write (4 consecutive keys of one q, XOR-swizzled);
    // lane-local sums. P rows are wave-private: no barrier needed before PV.
    float rs[2] = {0.f, 0.f};
#pragma unroll
    for (int mt = 0; mt < 2; mt++)
#pragma unroll
      for (int nt = 0; nt < 4; nt++) {
        bf16x4 pk4;
#pragma unroll
        for (int r = 0; r < 4; r++) {
          float p = exp2f(st[mt][nt][r]);
          rs[mt] += p;
          pk4[r] = (bf16)p;
        }
        int pbyte = ((wave * 32 + mt * 16 + l16) * 64 + nt * 16 + quad * 4) * 2;
        pbyte ^= (l16 & 7) << 4;
        *(bf16x4*)((char*)Psh + pbyte) = pk4;
      }
#pragma unroll
    for (int mt = 0; mt < 2; mt++) {
      float t2 = rs[mt];
      t2 += __shfl_xor(t2, 16);
      t2 += __shfl_xor(t2, 32);
      lrun[mt] += t2;
    }

    // O += P @ V  (P rows are this wave's own rows)
#pragma unroll
    for (int kk2 = 0; kk2 < 2; kk2++) {
      bf16x8 pf[2], vf[8];
#pragma unroll
      for (int mt = 0; mt < 2; mt++) {
        int pbyte = ((wave * 32 + mt * 16 + l16) * 64 + kk2 * 32 + quad * 8) * 2;
        pbyte ^= (l16 & 7) << 4;
        pf[mt] = *(const bf16x8*)((char*)Psh + pbyte);
      }
#pragma unroll
      for (int nt = 0; nt < 8; nt++) {
        int p = (4 * kk2 + quad) ^ l7;  // physical chunk (un-swizzle)
        vf[nt] = *(const bf16x8*)&Vsh[cur][(nt * 16 + l16) * KTS + p * 8];
      }
      __builtin_amdgcn_s_setprio(1);
#pragma unroll
      for (int mt = 0; mt < 2; mt++)
#pragma unroll
        for (int nt = 0; nt < 8; nt++)
          oacc[mt][nt] = __builtin_amdgcn_mfma_f32_16x16x32_bf16(pf[mt], vf[nt], oacc[mt][nt], 0, 0, 0);
      __builtin_amdgcn_s_setprio(0);
    }

    __builtin_amdgcn_s_barrier();  // all waves done reading tile t -> buf free for t+2
  }

  // epilogue: O[q][h*128+d] = oacc / l.  l for q=mt*16+x lives at lanes with l16=x.
#pragma unroll
  for (int mt = 0; mt < 2; mt++) {
    float inv[4];
#pragma unroll
    for (int r = 0; r < 4; r++)
      inv[r] = 1.0f / __shfl(lrun[mt], (lane & 48) | (quad * 4 + r));
#pragma unroll
    for (int nt = 0; nt < 8; nt++)
#pragma unroll
      for (int r = 0; r < 4; r++) {
        int q = qrow + mt * 16 + quad * 4 + r;
        int d = nt * 16 + l16;
        O[(size_t)(b * SEQ + q) * HIDDEN + h * HD + d] = (bf16)(oacc[mt][nt][r] * inv[r]);
      }
  }
}

extern "C" void kernel_launch(void* const* d_in, const int* in_sizes, int n_in,
                              void* d_out, int out_size, void* d_ws, size_t ws_size,
                              hipStream_t stream) {
  const float* hs = (const float*)d_in[0];
  const float* Wq = (const float*)d_in[1];
  const float* bq = (const float*)d_in[2];
  const float* Wk = (const float*)d_in[3];
  const float* bk = (const float*)d_in[4];
  const float* Wv = (const float*)d_in[5];
  const float* bv = (const float*)d_in[6];
  const float* Wo = (const float*)d_in[7];
  const float* bo = (const float*)d_in[8];
  float* out = (float*)d_out;

  char* ws = (char*)d_ws;
  bf16*  Abf   = (bf16*)(ws);                    // 4096*2048*2   = 16,777,216
  bf16*  WtQKV = (bf16*)(ws + 16777216);         // 6144*2048*2   = 25,165,824
  bf16*  WtO   = (bf16*)(ws + 41943040);         // 2048*2048*2   =  8,388,608
  float* biasQ = (float*)(ws + 50331648);        // 6144*4        =     24,576
  bf16*  QKV   = (bf16*)(ws + 50356224);         // 4096*6144*2   = 50,331,648
  bf16*  VT    = (bf16*)(ws + 100687872);        // 32*128*2048*2 = 16,777,216
  bf16*  Obf   = (bf16*)(ws + 117465088);        // 4096*2048*2   = 16,777,216
  // total 134,242,304 bytes of d_ws

  dim3 tb(32, 8);
  cast_f32_bf16_kernel<<<8192, 256, 0, stream>>>(hs, Abf, 2097152);
  transpose_cast4_kernel<<<dim3(64, 64, 4), tb, 0, stream>>>(
      Wq, Wk, Wv, Wo,
      WtQKV, WtQKV + 2048 * 2048, WtQKV + 2 * 2048 * 2048, WtO);
  concat3_kernel<<<24, 256, 0, stream>>>(bq, bk, bv, biasQ);

  // QKV: 256x256 depth-2 pipelined kernel, grid 16x24 = 384 blocks.
  gemm_bt_bias_256<bf16><<<dim3(16, 24), 512, 0, stream>>>(Abf, WtQKV, biasQ, QKV, NQKV, HIDDEN);
  transpose_v_kernel<<<dim3(64, 4, 32), tb, 0, stream>>>(QKV, VT);
  flash_attn_kernel<<<dim3(16, 32), 256, 0, stream>>>(QKV, VT, Obf);
  // O-proj: proven 128x128 kernel, grid 32x16 = 512 blocks.
  gemm_bt_bias<float><<<dim3(32, 16), 256, 0, stream>>>(Obf, WtO, bo, out, HIDDEN, HIDDEN);
}

// Round 5
// 395.312 us; speedup vs baseline: 1.0447x; 1.0330x over previous
//
#include <hip/hip_runtime.h>
#include <math.h>

typedef __bf16 bf16;
typedef __bf16 bf16x4 __attribute__((ext_vector_type(4)));
typedef __bf16 bf16x8 __attribute__((ext_vector_type(8)));
typedef float  f32x4  __attribute__((ext_vector_type(4)));
typedef float  f32x16 __attribute__((ext_vector_type(16)));

#define HIDDEN 2048
#define NH     16
#define HD     128
#define BATCH  2
#define SEQ    2048
#define MROWS  (BATCH*SEQ)   // 4096
#define NQKV   (3*HIDDEN)    // 6144

// async global->LDS, 16B per lane. LDS dest must be wave-uniform base + lane*16.
__device__ __forceinline__ void async16(const bf16* g, bf16* l) {
  __builtin_amdgcn_global_load_lds(
      (const __attribute__((address_space(1))) void*)g,
      (__attribute__((address_space(3))) void*)l, 16, 0, 0);
}

// ---------------- fused prep: weight transpose+cast (z<4), hs cast + bias concat (z==4) ----
// grid (64,64,5), block (32,8). Replaces 3 launches with 1.
__global__ __launch_bounds__(256) void prep_kernel(
    const float* __restrict__ hs,
    const float* __restrict__ Wq, const float* __restrict__ Wk,
    const float* __restrict__ Wv, const float* __restrict__ Wo,
    const float* __restrict__ bq, const float* __restrict__ bk,
    const float* __restrict__ bv,
    bf16* __restrict__ Abf, bf16* __restrict__ WtQKV, bf16* __restrict__ WtO,
    float* __restrict__ biasQ) {
  const int z = blockIdx.z;
  if (z < 4) {
    const float* src; bf16* dst;
    switch (z) {
      case 0: src = Wq; dst = WtQKV; break;
      case 1: src = Wk; dst = WtQKV + 2048 * 2048; break;
      case 2: src = Wv; dst = WtQKV + 2 * 2048 * 2048; break;
      default: src = Wo; dst = WtO; break;
    }
    __shared__ float t[32][33];
    int x  = blockIdx.x * 32 + threadIdx.x;
    int y0 = blockIdx.y * 32;
#pragma unroll
    for (int i = 0; i < 32; i += 8)
      t[threadIdx.y + i][threadIdx.x] = src[(size_t)(y0 + threadIdx.y + i) * HIDDEN + x];
    __syncthreads();
    int xo  = blockIdx.y * 32 + threadIdx.x;
    int yo0 = blockIdx.x * 32;
#pragma unroll
    for (int i = 0; i < 32; i += 8)
      dst[(size_t)(yo0 + threadIdx.y + i) * HIDDEN + xo] = (bf16)t[threadIdx.x][threadIdx.y + i];
  } else {
    // cast 2,097,152 float4 of hidden_state -> bf16; 4096 blocks x 512 each
    const int bid = blockIdx.y * 64 + blockIdx.x;
    const int tid = threadIdx.y * 32 + threadIdx.x;
    int base = bid * 512 + tid;
#pragma unroll
    for (int p = 0; p < 2; p++) {
      float4 f = ((const float4*)hs)[base + p * 256];
      bf16x4 o;
      o[0] = (bf16)f.x; o[1] = (bf16)f.y; o[2] = (bf16)f.z; o[3] = (bf16)f.w;
      ((bf16x4*)Abf)[base + p * 256] = o;
    }
    if (bid < 24) {   // bias concat (6144 floats)
      int i = bid * 256 + tid;
      biasQ[i] = (i < 2048) ? bq[i] : (i < 4096 ? bk[i - 2048] : bv[i - 4096]);
    }
  }
}

// ---------------- per-head V transpose: QKV V-part (s,d) -> Vt (bh, d, s) ----------------
__global__ __launch_bounds__(256) void transpose_v_kernel(
    const bf16* __restrict__ QKV, bf16* __restrict__ Vt) {
  __shared__ bf16 t[32][33];
  int bh = blockIdx.z, b = bh >> 4, h = bh & 15;
  const bf16* src = QKV + (size_t)b * SEQ * NQKV + 2 * HIDDEN + h * HD;  // [s][d], stride NQKV
  bf16* dst = Vt + (size_t)bh * HD * SEQ;                                 // [d][s], stride SEQ
  int s0 = blockIdx.x * 32, d0 = blockIdx.y * 32;
#pragma unroll
  for (int i = 0; i < 32; i += 8)
    t[threadIdx.y + i][threadIdx.x] = src[(size_t)(s0 + threadIdx.y + i) * NQKV + d0 + threadIdx.x];
  __syncthreads();
#pragma unroll
  for (int i = 0; i < 32; i += 8)
    dst[(size_t)(d0 + threadIdx.y + i) * SEQ + s0 + threadIdx.x] = t[threadIdx.x][threadIdx.y + i];
}

// ---------------- GEMM: C[M,N] = A[M,K] @ Bt[N,K]^T + bias, bf16 in, fp32 acc ----------------
// Proven m97-style 128x128 structure (888 TF @ 16x16x32), now with v_mfma_f32_32x32x16_bf16:
// same LDS bytes, -17% matrix-pipe cycles (8.07 vs 2x4.85 cyc per 32K FLOP) and half the
// MFMA instructions. 4 waves (2x2), per-wave 64x64 = 2x2 tiles of 32x32, acc 4x f32x16.
// Operand layout (32x32x16): A/B lane row/col = lane&31, k-chunk = (lane>>5)*8 + e.
// A and B share the identical k-map, so the result is invariant to its exact permutation.
// C/D: col = lane&31, row = (reg&3) + 8*(reg>>2) + 4*(lane>>5)  [guide-verified m74/m101].
// Rotation swizzle unchanged: physical chunk = (logical + row&7)&7; logical chunk for
// (ks, khalf) = ks*2 + khalf. Quarter-wave bank aliasing is 2-way (free).
template <typename OutT>
__global__ __launch_bounds__(256) void gemm_bt_bias(
    const bf16* __restrict__ A, const bf16* __restrict__ Bt,
    const float* __restrict__ bias, OutT* __restrict__ C, int N, int K) {
  __shared__ bf16 Ash[128 * 64];
  __shared__ bf16 Bsh[128 * 64];
  const int tid = threadIdx.x;
  const int wave = tid >> 6, lane = tid & 63;
  const int l32 = lane & 31, khalf = lane >> 5, l7 = l32 & 7;
  const int wm = (wave & 1) * 64, wn = (wave >> 1) * 64;
  const int m0 = blockIdx.x * 128, n0 = blockIdx.y * 128;

  f32x16 acc[2][2];
#pragma unroll
  for (int i = 0; i < 2; i++)
#pragma unroll
    for (int j = 0; j < 2; j++)
#pragma unroll
      for (int e = 0; e < 16; e++) acc[i][j][e] = 0.f;

  const int crow = tid >> 3, ccc = tid & 7;       // 32 rows/pass, 8 chunks/row
  const int cd = (ccc - crow) & 7;                // data chunk staged at physical ccc

  const bf16* pa[4];
  const bf16* pb[4];
#pragma unroll
  for (int s = 0; s < 4; s++) {
    pa[s] = &A[(size_t)(m0 + s * 32 + crow) * K + cd * 8];
    pb[s] = &Bt[(size_t)(n0 + s * 32 + crow) * K + cd * 8];
  }

  for (int kt = 0; kt < K; kt += 64) {
    __syncthreads();
#pragma unroll
    for (int s = 0; s < 4; s++) {
      async16(pa[s], &Ash[s * 2048 + tid * 8]);
      async16(pb[s], &Bsh[s * 2048 + tid * 8]);
      pa[s] += 64; pb[s] += 64;
    }
    __syncthreads();

#pragma unroll
    for (int ks = 0; ks < 4; ks++) {
      const int pc = (ks * 2 + khalf + l7) & 7;   // physical chunk (un-rotate)
      bf16x8 af[2], bfr[2];
#pragma unroll
      for (int mi = 0; mi < 2; mi++)
        af[mi]  = *(const bf16x8*)&Ash[(wm + mi * 32 + l32) * 64 + pc * 8];
#pragma unroll
      for (int nj = 0; nj < 2; nj++)
        bfr[nj] = *(const bf16x8*)&Bsh[(wn + nj * 32 + l32) * 64 + pc * 8];
#pragma unroll
      for (int mi = 0; mi < 2; mi++)
#pragma unroll
        for (int nj = 0; nj < 2; nj++)
          acc[mi][nj] = __builtin_amdgcn_mfma_f32_32x32x16_bf16(af[mi], bfr[nj], acc[mi][nj], 0, 0, 0);
    }
  }

  // C/D: col = l32 (n), row = 4*khalf + 8*g + r (m)
#pragma unroll
  for (int nj = 0; nj < 2; nj++) {
    int n = n0 + wn + nj * 32 + l32;
    float bv = bias[n];
#pragma unroll
    for (int mi = 0; mi < 2; mi++)
#pragma unroll
      for (int g = 0; g < 4; g++)
#pragma unroll
        for (int r = 0; r < 4; r++) {
          int m = m0 + wm + mi * 32 + 4 * khalf + 8 * g + r;
          C[(size_t)m * N + n] = (OutT)(acc[mi][nj][g * 4 + r] + bv);
        }
  }
}

// ---------------- flash attention, double-buffered K/V (r3 version, verified) ----------------
#define KTS   64

__global__ __launch_bounds__(256, 2) void flash_attn_kernel(
    const bf16* __restrict__ QKV, const bf16* __restrict__ Vt, bf16* __restrict__ O) {
  // XCD-aware swizzle of the 512-block grid (16 q-blocks x 32 bh)
  const int fid = blockIdx.x + 16 * blockIdx.y;
  const int nid = (fid & 7) * 64 + (fid >> 3);   // XCD x owns bh 4x..4x+3, all q-blocks
  const int bh = nid >> 4, b = bh >> 4, h = bh & 15;
  const int q0 = (nid & 15) * 128;
  const int tid = threadIdx.x, wave = tid >> 6, lane = tid & 63, quad = lane >> 4, l16 = lane & 15;

  const bf16* Qb  = QKV + (size_t)b * SEQ * NQKV + h * HD;            // Q[s][d], stride NQKV
  const bf16* Kb  = QKV + (size_t)b * SEQ * NQKV + HIDDEN + h * HD;   // K[s][d], stride NQKV
  const bf16* Vtb = Vt + (size_t)bh * HD * SEQ;                       // Vt[d][s], stride SEQ

  __shared__ bf16 Ksh[2][KTS * HD];  // [key][d], swizzled chunks, 2 x 16 KB
  __shared__ bf16 Vsh[2][HD * KTS];  // [d][key], swizzled chunks, 2 x 16 KB
  __shared__ bf16 Psh[128 * 64];     // [q][key], XOR-swizzled, 16 KB

  const int qrow = q0 + wave * 32;
  const float sc = 0.08838834764831845f * 1.44269504088896340f;  // 1/sqrt(128) * log2(e)

  // Q fragments (B-operand; lane layout as before), pre-scaled by sc
  bf16x8 qf[2][4];
#pragma unroll
  for (int mt = 0; mt < 2; mt++)
#pragma unroll
    for (int kk = 0; kk < 4; kk++) {
      bf16x8 t = *(const bf16x8*)&Qb[(size_t)(qrow + mt * 16 + l16) * NQKV + kk * 32 + quad * 8];
#pragma unroll
      for (int j = 0; j < 8; j++) t[j] = (bf16)((float)t[j] * sc);
      qf[mt][kk] = t;
    }

  const f32x4 zero4 = {0.f, 0.f, 0.f, 0.f};
  f32x4 oacc[2][8];
#pragma unroll
  for (int mt = 0; mt < 2; mt++)
#pragma unroll
    for (int nt = 0; nt < 8; nt++) oacc[mt][nt] = zero4;

  float lrun[2] = {0.f, 0.f};   // per-lane: l for q = qrow + mt*16 + l16

  const int krp = tid >> 4, kpp = tid & 15;  // K staging: physical row/chunk
  const int vrp = tid >> 3, vpp = tid & 7;   // V staging
  const int l7 = l16 & 7;

  // hoisted staging pointers (global side carries the rotation pre-swizzle)
  const bf16* pk[4];
  const bf16* pv[4];
#pragma unroll
  for (int s = 0; s < 4; s++) {
    int r  = s * 16 + krp;
    pk[s] = &Kb[(size_t)r * NQKV + (kpp ^ (r & 7)) * 8];
    int rv = s * 32 + vrp;
    pv[s] = &Vtb[(size_t)rv * SEQ + (vpp ^ (rv & 7)) * 8];
  }

  // ---- prologue: stage tile 0 into buf 0 ----
#pragma unroll
  for (int s = 0; s < 4; s++) {
    async16(pk[s], &Ksh[0][s * 2048 + tid * 8]);
    async16(pv[s], &Vsh[0][s * 2048 + tid * 8]);
    pk[s] += (size_t)KTS * NQKV;
    pv[s] += KTS;
  }

  const int NT = SEQ / KTS;   // 32
  for (int t = 0; t < NT; ++t) {
    const int cur = t & 1;
    if (t + 1 < NT) {
#pragma unroll
      for (int s = 0; s < 4; s++) {
        async16(pk[s], &Ksh[cur ^ 1][s * 2048 + tid * 8]);
        async16(pv[s], &Vsh[cur ^ 1][s * 2048 + tid * 8]);
        pk[s] += (size_t)KTS * NQKV;
        pv[s] += KTS;
      }
      asm volatile("s_waitcnt vmcnt(8)" ::: "memory");  // oldest 8 = tile t landed
    } else {
      asm volatile("s_waitcnt vmcnt(0)" ::: "memory");
    }
    __builtin_amdgcn_s_barrier();  // every wave's tile-t loads landed -> LDS consistent

    // S^T = K @ Qs^T : C col = l16 = q, row = quad*4+r = key
    f32x4 st[2][4];
#pragma unroll
    for (int mt = 0; mt < 2; mt++)
#pragma unroll
      for (int nt = 0; nt < 4; nt++) st[mt][nt] = zero4;
#pragma unroll
    for (int kk = 0; kk < 4; kk++) {
      const int p = (4 * kk + quad) ^ l7;   // physical chunk (un-swizzle)
      bf16x8 kf[4];
#pragma unroll
      for (int nt = 0; nt < 4; nt++)
        kf[nt] = *(const bf16x8*)&Ksh[cur][(nt * 16 + l16) * HD + p * 8];
      __builtin_amdgcn_s_setprio(1);
#pragma unroll
      for (int mt = 0; mt < 2; mt++)
#pragma unroll
        for (int nt = 0; nt < 4; nt++)
          st[mt][nt] = __builtin_amdgcn_mfma_f32_16x16x32_bf16(kf[nt], qf[mt][kk], st[mt][nt], 0, 0, 0);
      __builtin_amdgcn_s_setprio(0);
    }

    // p = exp2(s); packed b64 P-write (4 consecutive keys of one q, XOR-swizzled);
    // lane-local sums. P rows are wave-private: no barrier needed before PV.
    float rs[2] = {0.f, 0.f};
#pragma unroll
    for (int mt = 0; mt < 2; mt++)
#pragma unroll
      for (int nt = 0; nt < 4; nt++) {
        bf16x4 pk4;
#pragma unroll
        for (int r = 0; r < 4; r++) {
          float p = exp2f(st[mt][nt][r]);
          rs[mt] += p;
          pk4[r] = (bf16)p;
        }
        int pbyte = ((wave * 32 + mt * 16 + l16) * 64 + nt * 16 + quad * 4) * 2;
        pbyte ^= (l16 & 7) << 4;
        *(bf16x4*)((char*)Psh + pbyte) = pk4;
      }
#pragma unroll
    for (int mt = 0; mt < 2; mt++) {
      float t2 = rs[mt];
      t2 += __shfl_xor(t2, 16);
      t2 += __shfl_xor(t2, 32);
      lrun[mt] += t2;
    }

    // O += P @ V  (P rows are this wave's own rows)
#pragma unroll
    for (int kk2 = 0; kk2 < 2; kk2++) {
      bf16x8 pf[2], vf[8];
#pragma unroll
      for (int mt = 0; mt < 2; mt++) {
        int pbyte = ((wave * 32 + mt * 16 + l16) * 64 + kk2 * 32 + quad * 8) * 2;
        pbyte ^= (l16 & 7) << 4;
        pf[mt] = *(const bf16x8*)((char*)Psh + pbyte);
      }
#pragma unroll
      for (int nt = 0; nt < 8; nt++) {
        int p = (4 * kk2 + quad) ^ l7;  // physical chunk (un-swizzle)
        vf[nt] = *(const bf16x8*)&Vsh[cur][(nt * 16 + l16) * KTS + p * 8];
      }
      __builtin_amdgcn_s_setprio(1);
#pragma unroll
      for (int mt = 0; mt < 2; mt++)
#pragma unroll
        for (int nt = 0; nt < 8; nt++)
          oacc[mt][nt] = __builtin_amdgcn_mfma_f32_16x16x32_bf16(pf[mt], vf[nt], oacc[mt][nt], 0, 0, 0);
      __builtin_amdgcn_s_setprio(0);
    }

    __builtin_amdgcn_s_barrier();  // all waves done reading tile t -> buf free for t+2
  }

  // epilogue: O[q][h*128+d] = oacc / l.  l for q=mt*16+x lives at lanes with l16=x.
#pragma unroll
  for (int mt = 0; mt < 2; mt++) {
    float inv[4];
#pragma unroll
    for (int r = 0; r < 4; r++)
      inv[r] = 1.0f / __shfl(lrun[mt], (lane & 48) | (quad * 4 + r));
#pragma unroll
    for (int nt = 0; nt < 8; nt++)
#pragma unroll
      for (int r = 0; r < 4; r++) {
        int q = qrow + mt * 16 + quad * 4 + r;
        int d = nt * 16 + l16;
        O[(size_t)(b * SEQ + q) * HIDDEN + h * HD + d] = (bf16)(oacc[mt][nt][r] * inv[r]);
      }
  }
}

extern "C" void kernel_launch(void* const* d_in, const int* in_sizes, int n_in,
                              void* d_out, int out_size, void* d_ws, size_t ws_size,
                              hipStream_t stream) {
  const float* hs = (const float*)d_in[0];
  const float* Wq = (const float*)d_in[1];
  const float* bq = (const float*)d_in[2];
  const float* Wk = (const float*)d_in[3];
  const float* bk = (const float*)d_in[4];
  const float* Wv = (const float*)d_in[5];
  const float* bv = (const float*)d_in[6];
  const float* Wo = (const float*)d_in[7];
  const float* bo = (const float*)d_in[8];
  float* out = (float*)d_out;

  char* ws = (char*)d_ws;
  bf16*  Abf   = (bf16*)(ws);                    // 4096*2048*2   = 16,777,216
  bf16*  WtQKV = (bf16*)(ws + 16777216);         // 6144*2048*2   = 25,165,824
  bf16*  WtO   = (bf16*)(ws + 41943040);         // 2048*2048*2   =  8,388,608
  float* biasQ = (float*)(ws + 50331648);        // 6144*4        =     24,576
  bf16*  QKV   = (bf16*)(ws + 50356224);         // 4096*6144*2   = 50,331,648
  bf16*  VT    = (bf16*)(ws + 100687872);        // 32*128*2048*2 = 16,777,216
  bf16*  Obf   = (bf16*)(ws + 117465088);        // 4096*2048*2   = 16,777,216
  // total 134,242,304 bytes of d_ws

  dim3 tb(32, 8);
  // fused prep: weight transposes (z<4) + hs cast + bias concat (z==4)
  prep_kernel<<<dim3(64, 64, 5), tb, 0, stream>>>(
      hs, Wq, Wk, Wv, Wo, bq, bk, bv,
      Abf, WtQKV, WtO, biasQ);

  gemm_bt_bias<bf16><<<dim3(32, 48), 256, 0, stream>>>(Abf, WtQKV, biasQ, QKV, NQKV, HIDDEN);
  transpose_v_kernel<<<dim3(64, 4, 32), tb, 0, stream>>>(QKV, VT);
  flash_attn_kernel<<<dim3(16, 32), 256, 0, stream>>>(QKV, VT, Obf);
  gemm_bt_bias<float><<<dim3(32, 16), 256, 0, stream>>>(Obf, WtO, bo, out, HIDDEN, HIDDEN);
}